// Round 17
// baseline (93.666 us; speedup 1.0000x reference)
//
#include <hip/hip_runtime.h>

typedef __attribute__((ext_vector_type(8))) short bf16x8;
typedef __attribute__((ext_vector_type(4))) float f32x4;

#define FROW   4224                     // 66 cols * 64 B per LDS feature row
#define FBUF4  25344                    // 6 rows (4-row block + halo)
#define BTRIO  12288                    // 3 taps * 4096 B
#define LDS_T2 (2 * FBUF4 + 2 * BTRIO)  // 75264 B -> 2 blocks/CU

static __device__ __forceinline__ unsigned short f2bf(float f) {
  union { float f; unsigned u; } v; v.f = f;
  unsigned r = v.u + 0x7fffu + ((v.u >> 16) & 1u);
  return (unsigned short)(r >> 16);
}

static __device__ __forceinline__ void gload16(const void* g, void* l) {
  __builtin_amdgcn_global_load_lds(
      (const __attribute__((address_space(1))) void*)g,
      (__attribute__((address_space(3))) void*)l, 16, 0, 0);
}

// ---- DPP lane-shift helpers (16-lane rows == l15 groups; lg preserved) ----
// shr1: lane l15 <- l15-1 of cur; lane0 <- lane15 of prev (row_shl:15 patch)
static __device__ __forceinline__ bf16x8 bp_shr1(bf16x8 cur, bf16x8 prev) {
  union { bf16x8 v; int d[4]; } c, p, r;
  c.v = cur; p.v = prev;
#pragma unroll
  for (int i = 0; i < 4; ++i) {
    int t = __builtin_amdgcn_update_dpp(0, p.d[i], 0x10F, 0xF, 0xF, false);
    r.d[i] = __builtin_amdgcn_update_dpp(t, c.d[i], 0x111, 0xF, 0xF, false);
  }
  return r.v;
}
// shr1 with zero fill at lane0 (image-left halo col 0 is zero)
static __device__ __forceinline__ bf16x8 bp_shr1_z(bf16x8 cur) {
  union { bf16x8 v; int d[4]; } c, r;
  c.v = cur;
#pragma unroll
  for (int i = 0; i < 4; ++i)
    r.d[i] = __builtin_amdgcn_update_dpp(0, c.d[i], 0x111, 0xF, 0xF, true);
  return r.v;
}
// shl1: lane l15 <- l15+1 of cur; lane15 <- lane0 of next (row_shr:15 patch)
static __device__ __forceinline__ bf16x8 bp_shl1(bf16x8 cur, bf16x8 next) {
  union { bf16x8 v; int d[4]; } c, n, r;
  c.v = cur; n.v = next;
#pragma unroll
  for (int i = 0; i < 4; ++i) {
    int t = __builtin_amdgcn_update_dpp(0, n.d[i], 0x11F, 0xF, 0xF, false);
    r.d[i] = __builtin_amdgcn_update_dpp(t, c.d[i], 0x101, 0xF, 0xF, false);
  }
  return r.v;
}
// shl1 with zero fill at lane15 (image-right halo col 65 is zero)
static __device__ __forceinline__ bf16x8 bp_shl1_z(bf16x8 cur) {
  union { bf16x8 v; int d[4]; } c, r;
  c.v = cur;
#pragma unroll
  for (int i = 0; i < 4; ++i)
    r.d[i] = __builtin_amdgcn_update_dpp(0, c.d[i], 0x101, 0xF, 0xF, true);
  return r.v;
}

// ---------------- kernel F: feature expansion + fused weight pack ----------------
// fg: [c2(14)][b(32)][h(64)][w(64)][slot(4)][8ci] bf16, slot' = slot ^ (((w+1)>>1)&3)
// wpk: [it(126)][co(64)][slot(4)][8ci] bf16, slot' = slot ^ ((co>>1)&3)
__global__ void feats_k(const float* __restrict__ x, const float* __restrict__ sb,
                        const float* __restrict__ ss, const float* __restrict__ cf,
                        unsigned short* __restrict__ fg, unsigned short* __restrict__ wpk) {
  __shared__ __align__(16) unsigned short lds[64 * 456];
  const int b = blockIdx.x, h = blockIdx.y;
  const int tid = threadIdx.x;             // 256
  const int w = tid & 63, cig = tid >> 6;
  const int key = ((w + 1) >> 1) & 3;
  const int base = w * 456;
#pragma unroll
  for (int i = 0; i < 16; ++i) {
    int ci = cig * 16 + i;
    float v = x[(((size_t)b * 64 + ci) * 64 + h) * 64 + w];
    float sg = 1.0f / (1.0f + __expf(-v));
    float f0 = v * sg;
    float s1, c1;
    __sincosf(v, &s1, &c1);
    float c2v = c1 * c1 - s1 * s1, s2v = 2.0f * s1 * c1;
    float c3v = c1 * c2v - s1 * s2v, s3v = s1 * c2v + c1 * s2v;
    int q = ci >> 3;
    int half = q >> 2, qq = q & 3;
    int sl = (half * 4 + (qq ^ key)) * 8 + (ci & 7);
    lds[base + 0 * 64 + sl] = f2bf(f0);
    lds[base + 1 * 64 + sl] = f2bf(c1);
    lds[base + 2 * 64 + sl] = f2bf(c2v);
    lds[base + 3 * 64 + sl] = f2bf(c3v);
    lds[base + 4 * 64 + sl] = f2bf(s1);
    lds[base + 5 * 64 + sl] = f2bf(s2v);
    lds[base + 6 * 64 + sl] = f2bf(s3v);
  }
  __syncthreads();
#pragma unroll
  for (int k = 0; k < 14; ++k) {
    int u = tid + k * 256;
    int qs = u & 3;
    int ww = (u >> 2) & 63;
    int c2i = u >> 8;
    int cc = c2i >> 1, half = c2i & 1;
    uint4 v = *(const uint4*)&lds[ww * 456 + cc * 64 + (half * 4 + qs) * 8];
    unsigned short* dst = fg + ((size_t)(c2i * 32 + b) * 64 + h) * 2048 + (ww * 4 + qs) * 8;
    *(uint4*)dst = v;
  }
  if (tid < 126) {   // fused weight pack: 126 items per block
    int idx = (b * 64 + h) * 126 + tid;
    int e = idx & 7;
    int q = (idx >> 3) & 3;
    int co = (idx >> 5) & 63;
    int rest = idx >> 11;
    int tap = rest % 9;
    int c2p = rest / 9;
    int c = c2p >> 1, half = c2p & 1;
    int ci = half * 32 + q * 8 + e;
    int kh = tap / 3, kw = tap % 3;
    int wi = ((co * 64 + ci) * 3 + kh) * 3 + kw;
    float v;
    if (c == 0) {
      v = sb[wi];
    } else {
      int s = (c - 1) / 3, g = (c - 1) % 3;
      v = cf[(s * 36864 + wi) * 3 + g] * ss[wi];
    }
    wpk[((c2p * 9 + tap) * 64 + co) * 32 + ((q ^ ((co >> 1) & 3)) << 3) + e] = f2bf(v);
  }
}

// ---------------- kernel G: implicit GEMM, 2 blocks/CU + DPP kw-derivation ----------------
// grid (32 b, 16 hg) = 512 blocks = 2/CU. 4 waves/block; wave wid owns image row
// h0+wid: M=64 px x N=64 co, all 9 taps. Per kh: read ONLY the kw=1 (center) A
// fragments (4 ds_read_b128); kw=0/2 fragments are DPP lane-shifts of them with
// neighbor-fragment patches (image edges are exact zeros via halo cols 0/65).
// Cuts A-side LDS reads 3x; bit-identical results.
__global__ __launch_bounds__(256, 2) void gemm_k(
    const unsigned short* __restrict__ fg, const unsigned short* __restrict__ wpk,
    const float* __restrict__ bias, float* __restrict__ out) {
  extern __shared__ __align__(16) char smem[];
  const int b = blockIdx.x;
  const int h0 = blockIdx.y * 4;
  const int tid = threadIdx.x;
  const int lane = tid & 63;
  const int wid = tid >> 6;          // 0..3
  const int l15 = lane & 15;
  const int lg = lane >> 4;
  const char* fgB = (const char*)fg;
  const char* wpkB = (const char*)wpk;

  // zero never-staged bytes: halo cols + out-of-range rows (both feat buffers)
  for (int i = tid; i < 2 * FBUF4 / 4; i += 256) {
    int off = i * 4;
    int off2 = (off >= FBUF4) ? off - FBUF4 : off;
    int row = off2 / FROW;
    int cb = off2 - row * FROW;
    int hh = h0 - 1 + row;
    bool staged = ((unsigned)hh < 64u) && (cb >= 64) && (cb < 4160);
    if (!staged) ((int*)smem)[i] = 0;
  }

  // hoisted swizzled LDS offsets: A center (kw=1) and B
  int aoff1[4], boff[4];
#pragma unroll
  for (int cf = 0; cf < 4; ++cf) {
    int col = cf * 16 + l15 + 1;
    aoff1[cf] = col * 64 + ((lg ^ ((col >> 1) & 3)) << 4);
    int co = cf * 16 + l15;
    boff[cf] = co * 64 + ((lg ^ ((co >> 1) & 3)) << 4);
  }

  // stage B trio for (chunk cn, kh khn) into bdst: 12 gload16 over 4 waves
#define STAGE_TRIO(cn, khn, bdst)                                                \
  _Pragma("unroll")                                                              \
  for (int i = 0; i < 3; ++i) {                                                  \
    int u = i * 4 + wid;                                                         \
    gload16(wpkB + (size_t)((cn) * 9 + (khn) * 3 + (u >> 2)) * 4096 +            \
                (u & 3) * 1024 + lane * 16,                                      \
            (bdst) + (u >> 2) * 4096 + (u & 3) * 1024);                          \
  }
  // stage 8 of 24 feature calls (rows 0..5 x 4 parts) for chunk cn, phase kh
#define STAGE_F8(cn, khp, fdst)                                                  \
  _Pragma("unroll")                                                              \
  for (int j = 0; j < 2; ++j) {                                                  \
    int k = (khp) * 8 + wid * 2 + j;                                             \
    int row = k >> 2, part = k & 3;                                              \
    int hh = h0 - 1 + row;                                                       \
    if ((unsigned)hh < 64u)                                                      \
      gload16(fgB + ((size_t)((cn) * 2048 + b * 64 + hh)) * 4096 +               \
                  part * 1024 + lane * 16,                                       \
              (fdst) + row * FROW + 64 + part * 1024);                           \
  }
  // one MFMA cluster (16 MFMAs) with fragments Ar against B tap kwq
#define MFMA_CL(Ar, kwq)                                                         \
  {                                                                              \
    bf16x8 Bv[4];                                                                \
    _Pragma("unroll")                                                            \
    for (int nf = 0; nf < 4; ++nf)                                               \
      Bv[nf] = *(const bf16x8*)(bb + (kwq) * 4096 + boff[nf]);                   \
    __builtin_amdgcn_s_setprio(1);                                               \
    _Pragma("unroll")                                                            \
    for (int cfi = 0; cfi < 4; ++cfi)                                            \
      _Pragma("unroll")                                                          \
      for (int nf = 0; nf < 4; ++nf)                                             \
        acc[cfi][nf] = __builtin_amdgcn_mfma_f32_16x16x32_bf16(                  \
            Ar[cfi], Bv[nf], acc[cfi][nf], 0, 0, 0);                             \
    __builtin_amdgcn_s_setprio(0);                                               \
  }

  // prologue: feat chunk 0 (all 24) + B trio (0,0)
#pragma unroll
  for (int p = 0; p < 3; ++p) { STAGE_F8(0, p, smem) }
  STAGE_TRIO(0, 0, smem + 2 * FBUF4)
  __syncthreads();

  f32x4 acc[4][4];
#pragma unroll
  for (int cfi = 0; cfi < 4; ++cfi)
#pragma unroll
    for (int nf = 0; nf < 4; ++nf)
#pragma unroll
      for (int qq = 0; qq < 4; ++qq) acc[cfi][nf][qq] = 0.0f;

  for (int c2 = 0; c2 < 14; ++c2) {
    const char* f = smem + ((c2 & 1) ? FBUF4 : 0);
    char* fnext = smem + (((c2 + 1) & 1) ? FBUF4 : 0);
#pragma unroll
    for (int kh = 0; kh < 3; ++kh) {
      const int khg = c2 * 3 + kh;
      const char* bb = smem + 2 * FBUF4 + ((khg & 1) ? BTRIO : 0);
      if (khg < 41) {
        char* bnext = smem + 2 * FBUF4 + (((khg + 1) & 1) ? BTRIO : 0);
        const int cn = (khg + 1) / 3, khn = (khg + 1) % 3;
        STAGE_TRIO(cn, khn, bnext)
      }
      if (c2 < 13) { STAGE_F8(c2 + 1, kh, fnext) }

      const char* frow = f + (wid + kh) * FROW;
      bf16x8 A1[4];
#pragma unroll
      for (int cfi = 0; cfi < 4; ++cfi)
        A1[cfi] = *(const bf16x8*)(frow + aoff1[cfi]);

      MFMA_CL(A1, 1)                          // kw = 1 (center, direct)
      {
        bf16x8 Ad[4];                         // kw = 0: shift right, left edge 0
        Ad[0] = bp_shr1_z(A1[0]);
        Ad[1] = bp_shr1(A1[1], A1[0]);
        Ad[2] = bp_shr1(A1[2], A1[1]);
        Ad[3] = bp_shr1(A1[3], A1[2]);
        MFMA_CL(Ad, 0)
      }
      {
        bf16x8 Ad[4];                         // kw = 2: shift left, right edge 0
        Ad[0] = bp_shl1(A1[0], A1[1]);
        Ad[1] = bp_shl1(A1[1], A1[2]);
        Ad[2] = bp_shl1(A1[2], A1[3]);
        Ad[3] = bp_shl1_z(A1[3]);
        MFMA_CL(Ad, 2)
      }
      __syncthreads();
    }
  }
#undef STAGE_TRIO
#undef STAGE_F8
#undef MFMA_CL

  // epilogue: direct store (wave owns full K). C/D: col(l15)=co, row=lg*4+reg=w
  const int h = h0 + wid;
#pragma unroll
  for (int cfi = 0; cfi < 4; ++cfi) {
    int w4 = cfi * 16 + (lg << 2);
#pragma unroll
    for (int nf = 0; nf < 4; ++nf) {
      int co = nf * 16 + l15;
      float bv = bias[co];
      f32x4 v = acc[cfi][nf];
      f32x4 res;
      res[0] = v[0] + bv; res[1] = v[1] + bv; res[2] = v[2] + bv; res[3] = v[3] + bv;
      *(f32x4*)(out + ((size_t)(b * 64 + co) * 64 + h) * 64 + w4) = res;
    }
  }
}

// ---------------- fallback: naive fp32 direct (if ws too small) ----------------
__global__ void naive_k(const float* __restrict__ x, const float* __restrict__ sb,
                        const float* __restrict__ ss, const float* __restrict__ cf,
                        const float* __restrict__ bias, float* __restrict__ out) {
  int idx = blockIdx.x * 256 + threadIdx.x;
  if (idx >= 32 * 64 * 64 * 64) return;
  int w = idx & 63, h = (idx >> 6) & 63, co = (idx >> 12) & 63, b = idx >> 18;
  float acc = bias[co];
  for (int ci = 0; ci < 64; ++ci) {
    for (int kh = 0; kh < 3; ++kh) {
      int hh = h + kh - 1;
      if ((unsigned)hh >= 64u) continue;
      for (int kw = 0; kw < 3; ++kw) {
        int ww = w + kw - 1;
        if ((unsigned)ww >= 64u) continue;
        float v = x[((b * 64 + ci) * 64 + hh) * 64 + ww];
        int wi = ((co * 64 + ci) * 3 + kh) * 3 + kw;
        float s1, c1; __sincosf(v, &s1, &c1);
        float c2 = c1 * c1 - s1 * s1, s2 = 2.f * s1 * c1;
        float c3 = c1 * c2 - s1 * s2, s3 = s1 * c2 + c1 * s2;
        float t = sb[wi] * (v / (1.f + __expf(-v)));
        t += ss[wi] * (cf[wi * 3] * c1 + cf[wi * 3 + 1] * c2 + cf[wi * 3 + 2] * c3 +
                       cf[(36864 + wi) * 3] * s1 + cf[(36864 + wi) * 3 + 1] * s2 +
                       cf[(36864 + wi) * 3 + 2] * s3);
        acc += t;
      }
    }
  }
  out[idx] = acc;
}

extern "C" void kernel_launch(void* const* d_in, const int* in_sizes, int n_in,
                              void* d_out, int out_size, void* d_ws, size_t ws_size,
                              hipStream_t stream) {
  const float* x = (const float*)d_in[0];
  const float* sb = (const float*)d_in[1];
  const float* ss = (const float*)d_in[2];
  const float* cf = (const float*)d_in[3];
  const float* bias = (const float*)d_in[4];
  float* out = (float*)d_out;

  const size_t FEATS_OFF = 1u << 20;                          // wpk in first 1 MB
  const size_t NEED = FEATS_OFF + (size_t)14 * 32 * 64 * 4096; // ~118.5 MB
  if (ws_size >= NEED) {
    unsigned short* wpk = (unsigned short*)d_ws;
    unsigned short* fg = (unsigned short*)((char*)d_ws + FEATS_OFF);
    feats_k<<<dim3(32, 64), 256, 0, stream>>>(x, sb, ss, cf, fg, wpk);
    (void)hipFuncSetAttribute((const void*)gemm_k,
                              hipFuncAttributeMaxDynamicSharedMemorySize, LDS_T2);
    gemm_k<<<dim3(32, 16), 256, LDS_T2, stream>>>(fg, wpk, bias, out);
  } else {
    naive_k<<<32768, 256, 0, stream>>>(x, sb, ss, cf, bias, out);
  }
}

// Round 18
// 91.736 us; speedup vs baseline: 1.0210x; 1.0210x over previous
//
#include <hip/hip_runtime.h>

typedef __attribute__((ext_vector_type(8))) short bf16x8;
typedef __attribute__((ext_vector_type(4))) float f32x4;

#define FROW   4224                     // 66 cols * 64 B per LDS feature row
#define FBUF4  25344                    // 6 rows (4-row block + halo)
#define BTRIO  12288                    // 3 taps * 4096 B
#define LDS_T2 (2 * FBUF4 + 2 * BTRIO)  // 75264 B -> 2 blocks/CU

static __device__ __forceinline__ unsigned short f2bf(float f) {
  union { float f; unsigned u; } v; v.f = f;
  unsigned r = v.u + 0x7fffu + ((v.u >> 16) & 1u);
  return (unsigned short)(r >> 16);
}

static __device__ __forceinline__ void gload16(const void* g, void* l) {
  __builtin_amdgcn_global_load_lds(
      (const __attribute__((address_space(1))) void*)g,
      (__attribute__((address_space(3))) void*)l, 16, 0, 0);
}

// ---------------- kernel F: feature expansion + fused weight pack ----------------
// fg: [c2(14)][b(32)][h(64)][w(64)][slot(4)][8ci] bf16, slot' = slot ^ (((w+1)>>1)&3)
// wpk: [it(126)][co(64)][slot(4)][8ci] bf16, slot' = slot ^ ((co>>1)&3)
__global__ void feats_k(const float* __restrict__ x, const float* __restrict__ sb,
                        const float* __restrict__ ss, const float* __restrict__ cf,
                        unsigned short* __restrict__ fg, unsigned short* __restrict__ wpk) {
  __shared__ __align__(16) unsigned short lds[64 * 456];
  const int b = blockIdx.x, h = blockIdx.y;
  const int tid = threadIdx.x;             // 256
  const int w = tid & 63, cig = tid >> 6;
  const int key = ((w + 1) >> 1) & 3;
  const int base = w * 456;
#pragma unroll
  for (int i = 0; i < 16; ++i) {
    int ci = cig * 16 + i;
    float v = x[(((size_t)b * 64 + ci) * 64 + h) * 64 + w];
    float sg = 1.0f / (1.0f + __expf(-v));
    float f0 = v * sg;
    float s1, c1;
    __sincosf(v, &s1, &c1);
    float c2v = c1 * c1 - s1 * s1, s2v = 2.0f * s1 * c1;
    float c3v = c1 * c2v - s1 * s2v, s3v = s1 * c2v + c1 * s2v;
    int q = ci >> 3;
    int half = q >> 2, qq = q & 3;
    int sl = (half * 4 + (qq ^ key)) * 8 + (ci & 7);
    lds[base + 0 * 64 + sl] = f2bf(f0);
    lds[base + 1 * 64 + sl] = f2bf(c1);
    lds[base + 2 * 64 + sl] = f2bf(c2v);
    lds[base + 3 * 64 + sl] = f2bf(c3v);
    lds[base + 4 * 64 + sl] = f2bf(s1);
    lds[base + 5 * 64 + sl] = f2bf(s2v);
    lds[base + 6 * 64 + sl] = f2bf(s3v);
  }
  __syncthreads();
#pragma unroll
  for (int k = 0; k < 14; ++k) {
    int u = tid + k * 256;
    int qs = u & 3;
    int ww = (u >> 2) & 63;
    int c2i = u >> 8;
    int cc = c2i >> 1, half = c2i & 1;
    uint4 v = *(const uint4*)&lds[ww * 456 + cc * 64 + (half * 4 + qs) * 8];
    unsigned short* dst = fg + ((size_t)(c2i * 32 + b) * 64 + h) * 2048 + (ww * 4 + qs) * 8;
    *(uint4*)dst = v;
  }
  if (tid < 126) {   // fused weight pack: 126 items per block
    int idx = (b * 64 + h) * 126 + tid;
    int e = idx & 7;
    int q = (idx >> 3) & 3;
    int co = (idx >> 5) & 63;
    int rest = idx >> 11;
    int tap = rest % 9;
    int c2p = rest / 9;
    int c = c2p >> 1, half = c2p & 1;
    int ci = half * 32 + q * 8 + e;
    int kh = tap / 3, kw = tap % 3;
    int wi = ((co * 64 + ci) * 3 + kh) * 3 + kw;
    float v;
    if (c == 0) {
      v = sb[wi];
    } else {
      int s = (c - 1) / 3, g = (c - 1) % 3;
      v = cf[(s * 36864 + wi) * 3 + g] * ss[wi];
    }
    wpk[((c2p * 9 + tap) * 64 + co) * 32 + ((q ^ ((co >> 1) & 3)) << 3) + e] = f2bf(v);
  }
}

// ---------------- kernel G: implicit GEMM, 2 blocks/CU TLP + setprio ----------------
// grid (32 b, 16 hg) = 512 blocks = 2/CU (LDS 75.3 KB). 4 waves/block; wave wid
// owns image row h0+wid: M=64 px x N=64 co, ALL 9 taps. Two independent blocks
// per CU drift in phase (TLP = the one structural win: 70.8 -> 64.6 us).
// Measured-final configuration after 11 hypotheses; see session journal.
__global__ __launch_bounds__(256, 2) void gemm_k(
    const unsigned short* __restrict__ fg, const unsigned short* __restrict__ wpk,
    const float* __restrict__ bias, float* __restrict__ out) {
  extern __shared__ __align__(16) char smem[];
  const int b = blockIdx.x;
  const int h0 = blockIdx.y * 4;
  const int tid = threadIdx.x;
  const int lane = tid & 63;
  const int wid = tid >> 6;          // 0..3
  const int l15 = lane & 15;
  const int lg = lane >> 4;
  const char* fgB = (const char*)fg;
  const char* wpkB = (const char*)wpk;

  // zero never-staged bytes: halo cols + out-of-range rows (both feat buffers)
  for (int i = tid; i < 2 * FBUF4 / 4; i += 256) {
    int off = i * 4;
    int off2 = (off >= FBUF4) ? off - FBUF4 : off;
    int row = off2 / FROW;
    int cb = off2 - row * FROW;
    int hh = h0 - 1 + row;
    bool staged = ((unsigned)hh < 64u) && (cb >= 64) && (cb < 4160);
    if (!staged) ((int*)smem)[i] = 0;
  }

  // hoisted swizzled LDS offsets
  int aoff[4][3], boff[4];
#pragma unroll
  for (int cf = 0; cf < 4; ++cf) {
#pragma unroll
    for (int kw = 0; kw < 3; ++kw) {
      int col = cf * 16 + l15 + kw;
      aoff[cf][kw] = col * 64 + ((lg ^ ((col >> 1) & 3)) << 4);
    }
    int co = cf * 16 + l15;
    boff[cf] = co * 64 + ((lg ^ ((co >> 1) & 3)) << 4);
  }

  // stage B trio for (chunk cn, kh khn) into bdst: 12 gload16 over 4 waves
#define STAGE_TRIO(cn, khn, bdst)                                                \
  _Pragma("unroll")                                                              \
  for (int i = 0; i < 3; ++i) {                                                  \
    int u = i * 4 + wid;             /* 0..11: tap t=u>>2, part=u&3 */           \
    gload16(wpkB + (size_t)((cn) * 9 + (khn) * 3 + (u >> 2)) * 4096 +            \
                (u & 3) * 1024 + lane * 16,                                      \
            (bdst) + (u >> 2) * 4096 + (u & 3) * 1024);                          \
  }
  // stage 8 of 24 feature calls (rows 0..5 x 4 parts) for chunk cn, phase kh
#define STAGE_F8(cn, khp, fdst)                                                  \
  _Pragma("unroll")                                                              \
  for (int j = 0; j < 2; ++j) {                                                  \
    int k = (khp) * 8 + wid * 2 + j;  /* 0..23 */                                \
    int row = k >> 2, part = k & 3;                                              \
    int hh = h0 - 1 + row;                                                       \
    if ((unsigned)hh < 64u)                                                      \
      gload16(fgB + ((size_t)((cn) * 2048 + b * 64 + hh)) * 4096 +               \
                  part * 1024 + lane * 16,                                       \
              (fdst) + row * FROW + 64 + part * 1024);                           \
  }

  // prologue: feat chunk 0 (all 24) + B trio (0,0)
#pragma unroll
  for (int p = 0; p < 3; ++p) { STAGE_F8(0, p, smem) }
  STAGE_TRIO(0, 0, smem + 2 * FBUF4)
  __syncthreads();

  f32x4 acc[4][4];
#pragma unroll
  for (int cfi = 0; cfi < 4; ++cfi)
#pragma unroll
    for (int nf = 0; nf < 4; ++nf)
#pragma unroll
      for (int qq = 0; qq < 4; ++qq) acc[cfi][nf][qq] = 0.0f;

  for (int c2 = 0; c2 < 14; ++c2) {
    const char* f = smem + ((c2 & 1) ? FBUF4 : 0);
    char* fnext = smem + (((c2 + 1) & 1) ? FBUF4 : 0);
#pragma unroll
    for (int kh = 0; kh < 3; ++kh) {
      const int khg = c2 * 3 + kh;
      const char* bb = smem + 2 * FBUF4 + ((khg & 1) ? BTRIO : 0);
      // stage next B trio
      if (khg < 41) {
        char* bnext = smem + 2 * FBUF4 + (((khg + 1) & 1) ? BTRIO : 0);
        const int cn = (khg + 1) / 3, khn = (khg + 1) % 3;
        STAGE_TRIO(cn, khn, bnext)
      }
      // stage 8 feature calls for next chunk
      if (c2 < 13) { STAGE_F8(c2 + 1, kh, fnext) }

      const char* frow = f + (wid + kh) * FROW;
#pragma unroll
      for (int kw = 0; kw < 3; ++kw) {
        bf16x8 A[4], Bv[4];
#pragma unroll
        for (int cfi = 0; cfi < 4; ++cfi)
          A[cfi] = *(const bf16x8*)(frow + aoff[cfi][kw]);
#pragma unroll
        for (int nf = 0; nf < 4; ++nf)
          Bv[nf] = *(const bf16x8*)(bb + kw * 4096 + boff[nf]);
        __builtin_amdgcn_s_setprio(1);
#pragma unroll
        for (int cfi = 0; cfi < 4; ++cfi)
#pragma unroll
          for (int nf = 0; nf < 4; ++nf)
            acc[cfi][nf] = __builtin_amdgcn_mfma_f32_16x16x32_bf16(
                A[cfi], Bv[nf], acc[cfi][nf], 0, 0, 0);
        __builtin_amdgcn_s_setprio(0);
      }
      __syncthreads();
    }
  }
#undef STAGE_TRIO
#undef STAGE_F8

  // epilogue: direct store (wave owns full K). C/D: col(l15)=co, row=lg*4+reg=w
  const int h = h0 + wid;
#pragma unroll
  for (int cfi = 0; cfi < 4; ++cfi) {
    int w4 = cfi * 16 + (lg << 2);
#pragma unroll
    for (int nf = 0; nf < 4; ++nf) {
      int co = nf * 16 + l15;
      float bv = bias[co];
      f32x4 v = acc[cfi][nf];
      f32x4 res;
      res[0] = v[0] + bv; res[1] = v[1] + bv; res[2] = v[2] + bv; res[3] = v[3] + bv;
      *(f32x4*)(out + ((size_t)(b * 64 + co) * 64 + h) * 64 + w4) = res;
    }
  }
}

// ---------------- fallback: naive fp32 direct (if ws too small) ----------------
__global__ void naive_k(const float* __restrict__ x, const float* __restrict__ sb,
                        const float* __restrict__ ss, const float* __restrict__ cf,
                        const float* __restrict__ bias, float* __restrict__ out) {
  int idx = blockIdx.x * 256 + threadIdx.x;
  if (idx >= 32 * 64 * 64 * 64) return;
  int w = idx & 63, h = (idx >> 6) & 63, co = (idx >> 12) & 63, b = idx >> 18;
  float acc = bias[co];
  for (int ci = 0; ci < 64; ++ci) {
    for (int kh = 0; kh < 3; ++kh) {
      int hh = h + kh - 1;
      if ((unsigned)hh >= 64u) continue;
      for (int kw = 0; kw < 3; ++kw) {
        int ww = w + kw - 1;
        if ((unsigned)ww >= 64u) continue;
        float v = x[((b * 64 + ci) * 64 + hh) * 64 + ww];
        int wi = ((co * 64 + ci) * 3 + kh) * 3 + kw;
        float s1, c1; __sincosf(v, &s1, &c1);
        float c2 = c1 * c1 - s1 * s1, s2 = 2.f * s1 * c1;
        float c3 = c1 * c2 - s1 * s2, s3 = s1 * c2 + c1 * s2;
        float t = sb[wi] * (v / (1.f + __expf(-v)));
        t += ss[wi] * (cf[wi * 3] * c1 + cf[wi * 3 + 1] * c2 + cf[wi * 3 + 2] * c3 +
                       cf[(36864 + wi) * 3] * s1 + cf[(36864 + wi) * 3 + 1] * s2 +
                       cf[(36864 + wi) * 3 + 2] * s3);
        acc += t;
      }
    }
  }
  out[idx] = acc;
}

extern "C" void kernel_launch(void* const* d_in, const int* in_sizes, int n_in,
                              void* d_out, int out_size, void* d_ws, size_t ws_size,
                              hipStream_t stream) {
  const float* x = (const float*)d_in[0];
  const float* sb = (const float*)d_in[1];
  const float* ss = (const float*)d_in[2];
  const float* cf = (const float*)d_in[3];
  const float* bias = (const float*)d_in[4];
  float* out = (float*)d_out;

  const size_t FEATS_OFF = 1u << 20;                          // wpk in first 1 MB
  const size_t NEED = FEATS_OFF + (size_t)14 * 32 * 64 * 4096; // ~118.5 MB
  if (ws_size >= NEED) {
    unsigned short* wpk = (unsigned short*)d_ws;
    unsigned short* fg = (unsigned short*)((char*)d_ws + FEATS_OFF);
    feats_k<<<dim3(32, 64), 256, 0, stream>>>(x, sb, ss, cf, fg, wpk);
    (void)hipFuncSetAttribute((const void*)gemm_k,
                              hipFuncAttributeMaxDynamicSharedMemorySize, LDS_T2);
    gemm_k<<<dim3(32, 16), 256, LDS_T2, stream>>>(fg, wpk, bias, out);
  } else {
    naive_k<<<32768, 256, 0, stream>>>(x, sb, ss, cf, bias, out);
  }
}